// Round 24
// baseline (150.548 us; speedup 1.0000x reference)
//
#include <hip/hip_runtime.h>
#include <hip/hip_bf16.h>
#include <math.h>

// Problem dims
#define BBATCH 128
#define NCHAN  22
#define TLEN   1000
#define F1C    8
#define F2C    16
#define L1W    31
#define L2W    38
#define LSEQ   69
#define EDIM   16
#define NHEAD  8
#define FFDIM  64

// const block offsets (floats within ws)
#define C_SA   0
#define C_BA   16
#define C_BC2  32
#define C_AW   4144                     // packed bf16 A-frags branch2: 22*64*4 u32
#define C_AW1  (C_AW + 5632)            // branch1 A-frags: 22*4*64*4 u32
#define C_TOTAL (C_AW1 + 22528)

// ws layout (floats)
#define OFF_CONST 0
#define OFF_CHNK  40960
#define OFF_SEQ   (OFF_CHNK + 81920)
#define OFF_STB   (OFF_SEQ + 141312)
#define OFF_HBUF  (OFF_STB + 141312)

typedef __attribute__((ext_vector_type(8))) short bf16x8;
typedef __attribute__((ext_vector_type(4))) float f32x4;

static __device__ __forceinline__ unsigned short f2bf(float f) {
    unsigned u = __float_as_uint(f);
    unsigned r = (u + 0x7FFFu + ((u >> 16) & 1u)) >> 16;    // RNE
    return (unsigned short)r;
}

// broadcast-from-lane-i within 16-lane groups (wave64-safe)
#define SWZ(v, imm) __int_as_float(__builtin_amdgcn_ds_swizzle(__float_as_int(v), imm))
#define MV16(dst, sv, W) do { \
    float p0=SWZ(sv,0x010)*W[0],  p1=SWZ(sv,0x030)*W[1],  \
          p2=SWZ(sv,0x050)*W[2],  p3=SWZ(sv,0x070)*W[3],  \
          p4=SWZ(sv,0x090)*W[4],  p5=SWZ(sv,0x0B0)*W[5],  \
          p6=SWZ(sv,0x0D0)*W[6],  p7=SWZ(sv,0x0F0)*W[7],  \
          p8=SWZ(sv,0x110)*W[8],  p9=SWZ(sv,0x130)*W[9],  \
          p10=SWZ(sv,0x150)*W[10],p11=SWZ(sv,0x170)*W[11],\
          p12=SWZ(sv,0x190)*W[12],p13=SWZ(sv,0x1B0)*W[13],\
          p14=SWZ(sv,0x1D0)*W[14],p15=SWZ(sv,0x1F0)*W[15];\
    dst = (((p0+p1)+(p2+p3))+((p4+p5)+(p6+p7))) + (((p8+p9)+(p10+p11))+((p12+p13)+(p14+p15))); \
} while(0)

// ---------------- setup: parallelized across 24 blocks -------------------
__global__ void k_setup(const float* __restrict__ wsp1a, const float* __restrict__ b_spec1,
                        const float* __restrict__ g_bn1, const float* __restrict__ b_bn1,
                        const float* __restrict__ g_bn3, const float* __restrict__ b_bn3,
                        const float* __restrict__ w_spec2, const float* __restrict__ b_spec2,
                        const float* __restrict__ g_bn2, const float* __restrict__ b_bn2,
                        const float* __restrict__ w_sp2, const float* __restrict__ b_sp2,
                        const float* __restrict__ g_bn5, const float* __restrict__ b_bn5,
                        const float* __restrict__ w_spec1,
                        float* __restrict__ consts)
{
    int tid = threadIdx.x;
    int gb = blockIdx.x;
    int NG = gridDim.x;
    int gid = gb*256 + tid;
    float rbn = rsqrtf(1.0f + 1e-5f);
    if (gb == 0 && tid < 16) {
        int c2 = tid, c1 = c2 >> 1;
        float wsum = 0.f;
        for (int h = 0; h < NCHAN; h++) wsum += wsp1a[c2*NCHAN + h];
        float s1b = g_bn1[c1] * rbn;
        float s3  = g_bn3[c2] * rbn;
        float C1  = (s1b * b_spec1[c1] + b_bn1[c1]) * wsum;
        consts[C_SA + c2] = s3 * s1b;
        consts[C_BA + c2] = s3 * C1 + b_bn3[c2];
        float s5 = g_bn5[c2] * rbn;
        float acc = b_sp2[c2];
        for (int cc = 0; cc < F1C; cc++) {
            float s2b = g_bn2[cc] * rbn;
            float cb  = s2b * b_spec2[cc] + b_bn2[cc];
            float wsh = 0.f;
            for (int h = 0; h < NCHAN; h++) wsh += w_sp2[(c2*F1C + cc)*NCHAN + h];
            acc += wsh * cb;
        }
        consts[C_BC2 + c2] = s5 * acc + b_bn5[c2];
    }
    unsigned* aw = (unsigned*)&consts[C_AW];
    for (int idx = gid; idx < 22*64*4; idx += 256*NG) {
        int r = idx & 3;
        int l = (idx >> 2) & 63;
        int c = idx >> 8;
        int m = l & 15;
        int k0 = ((l >> 4) << 3) + 2*r;
        float s5 = g_bn5[m] * rbn;
        float w0 = 0.f, w1 = 0.f;
        for (int cc = 0; cc < F1C; cc++) {
            float f = w_sp2[(m*F1C + cc)*NCHAN + c] * (g_bn2[cc] * rbn);
            if (k0 < 30)     w0 += f * w_spec2[cc*30 + k0];
            if (k0 + 1 < 30) w1 += f * w_spec2[cc*30 + k0 + 1];
        }
        w0 *= s5; w1 *= s5;
        aw[idx] = (unsigned)f2bf(w0) | ((unsigned)f2bf(w1) << 16);
    }
    unsigned* aw1 = (unsigned*)&consts[C_AW1];
    for (int idx = gid; idx < 22*4*64*4; idx += 256*NG) {
        int r = idx & 3;
        int l = (idx >> 2) & 63;
        int kk = (idx >> 8) & 3;
        int c = idx >> 10;
        int m = l & 15;
        int klocal = ((l >> 4) << 3) + 2*r;
        int tap0 = kk*32 + klocal;
        float sa = (g_bn3[m] * rbn) * (g_bn1[m >> 1] * rbn);
        float base = sa * wsp1a[m*NCHAN + c];
        float w0 = (tap0     < 125) ? base * w_spec1[(m >> 1)*125 + tap0]     : 0.f;
        float w1 = (tap0 + 1 < 125) ? base * w_spec1[(m >> 1)*125 + tap0 + 1] : 0.f;
        aw1[idx] = (unsigned)f2bf(w0) | ((unsigned)f2bf(w1) << 16);
    }
}

// ---------------- merged front: b1mm (bid<512) + b2mm (bid>=512) --------
// Parity copies padded +16 shorts so copy offset is not 0 mod 128 bytes.
#define PB1 384
#define NW1 (NCHAN*PB1)          // 8448 shorts
#define CP1 (NW1 + 16)           // padded copy stride
#define PS1 257
#define PB2 288
#define NW2 (NCHAN*PB2)          // 6336 shorts
#define CP2 (NW2 + 16)
#define SQP2 257
#define FRONT_SM 12568           // (2*NW1+16)/2 = 8456 fl + 16*257 = 4112 fl

__device__ __forceinline__ void b1mm_body(float* smem, int bid,
    const float* __restrict__ x, const float* __restrict__ consts,
    const float* __restrict__ w_sp1b, const float* __restrict__ b_sp1b,
    const float* __restrict__ g_bn4, const float* __restrict__ b_bn4,
    float* __restrict__ seq)
{
    unsigned short* xs = (unsigned short*)smem;
    float* sq = smem + 8456;
    const uint4* __restrict__ awg = (const uint4*)&consts[C_AW1];
    int q = bid & 3, b = bid >> 2;
    int t0 = q * 256;
    int tid = threadIdx.x;

    for (int idx = tid; idx < NW1; idx += 256) {
        int h = idx / PB1, e = idx - h*PB1;
        int t = t0 - 62 + e;
        const float* xr = x + (b*NCHAN + h)*TLEN;
        float v0 = ((unsigned)t < 1000u && e < 380) ? xr[t] : 0.f;
        float v1 = ((unsigned)(t+1) < 1000u && e < 380) ? xr[t+1] : 0.f;
        xs[idx] = f2bf(v0);
        xs[CP1 + idx] = f2bf(v1);
    }
    __syncthreads();

    int lane = tid & 63, wid = tid >> 6;
    int tp = lane & 15;
    int kb = (lane >> 4) << 3;
    int P = tp & 1;
    int tb0 = wid * 64;
    const unsigned short* xb = xs + P*CP1 + (tb0 + tp + kb - P);

    f32x4 a0 = {0.f,0.f,0.f,0.f};
    f32x4 a1 = a0, a2 = a0, a3 = a0;
    for (int c = 0; c < NCHAN; c++) {
#pragma unroll
        for (int kk = 0; kk < 4; kk++) {
            uint4 au = awg[(c*4 + kk)*64 + lane];
            union Ua { uint4 qv; bf16x8 v; } A; A.qv = au;
            const unsigned short* row = xb + c*PB1 + kk*32;
            union Uv { bf16x8 v; unsigned u[4]; };
            Uv B0, B1, B2, B3;
#pragma unroll
            for (int r = 0; r < 4; r++) {
                B0.u[r] = *(const unsigned*)(row + 2*r);
                B1.u[r] = *(const unsigned*)(row + 16 + 2*r);
                B2.u[r] = *(const unsigned*)(row + 32 + 2*r);
                B3.u[r] = *(const unsigned*)(row + 48 + 2*r);
            }
            a0 = __builtin_amdgcn_mfma_f32_16x16x32_bf16(A.v, B0.v, a0, 0, 0, 0);
            a1 = __builtin_amdgcn_mfma_f32_16x16x32_bf16(A.v, B1.v, a1, 0, 0, 0);
            a2 = __builtin_amdgcn_mfma_f32_16x16x32_bf16(A.v, B2.v, a2, 0, 0, 0);
            a3 = __builtin_amdgcn_mfma_f32_16x16x32_bf16(A.v, B3.v, a3, 0, 0, 0);
        }
    }

    {
        int c2b = (lane >> 4) * 4;
        float ba[4];
#pragma unroll
        for (int r = 0; r < 4; r++) ba[r] = consts[C_BA + c2b + r];
#pragma unroll
        for (int r = 0; r < 4; r++) {
            float v, e;
            v = a0[r] + ba[r]; e = (v > 0.f) ? v : (expf(v) - 1.f);
            sq[(c2b+r)*PS1 + tb0 + tp +  0] = e;
            v = a1[r] + ba[r]; e = (v > 0.f) ? v : (expf(v) - 1.f);
            sq[(c2b+r)*PS1 + tb0 + tp + 16] = e;
            v = a2[r] + ba[r]; e = (v > 0.f) ? v : (expf(v) - 1.f);
            sq[(c2b+r)*PS1 + tb0 + tp + 32] = e;
            v = a3[r] + ba[r]; e = (v > 0.f) ? v : (expf(v) - 1.f);
            sq[(c2b+r)*PS1 + tb0 + tp + 48] = e;
        }
    }
    __syncthreads();

    {
        int u = tid;
        int w = 8*q + (u >> 5);
        float rbn = rsqrtf(1.0f + 1e-5f);
        float hv[16];
#pragma unroll
        for (int c = 0; c < 16; c++) hv[c] = sq[c*PS1 + u];
        float p[16];
#pragma unroll
        for (int c = 0; c < 16; c++) {
            float s = 0.f;
#pragma unroll
            for (int j = 0; j < 16; j++) s += w_sp1b[c*16 + j] * hv[j];
            float sc = g_bn4[c] * rbn;
            float a = sc * (s + b_sp1b[c]) + b_bn4[c];
            float g = (a > 0.f) ? a : (expf(a) - 1.f);
            g += __shfl_xor(g, 1, 64);
            g += __shfl_xor(g, 2, 64);
            g += __shfl_xor(g, 4, 64);
            g += __shfl_xor(g, 8, 64);
            g += __shfl_xor(g, 16, 64);
            p[c] = g;
        }
        if ((u & 31) == 0 && w < L1W) {
            float* sp = &seq[(b*LSEQ + w)*16];
#pragma unroll
            for (int i = 0; i < 4; i++)
                *(float4*)&sp[4*i] = make_float4(p[4*i]*(1.f/32.f), p[4*i+1]*(1.f/32.f),
                                                 p[4*i+2]*(1.f/32.f), p[4*i+3]*(1.f/32.f));
        }
    }
}

__device__ __forceinline__ void b2mm_body(float* smem, int bid,
    const float* __restrict__ x, const float* __restrict__ consts,
    float* __restrict__ chnk)
{
    unsigned short* xs = (unsigned short*)smem;
    float* sq = smem + 6344;     // (2*NW2+16)/2
    const unsigned* __restrict__ awg = (const unsigned*)&consts[C_AW];
    int q = bid & 3, b = bid >> 2;
    int t0 = q * 250;
    int tid = threadIdx.x;

    for (int idx = tid; idx < NW2; idx += 256) {
        int h = idx / PB2, e = idx - h*PB2;
        int t = t0 - 14 + e;
        const float* xr = x + (b*NCHAN + h)*TLEN;
        float v0 = ((unsigned)t < 1000u) ? xr[t] : 0.f;
        float v1 = ((unsigned)(t+1) < 1000u) ? xr[t+1] : 0.f;
        xs[idx] = f2bf(v0);
        xs[CP2 + idx] = f2bf(v1);
    }
    __syncthreads();

    int lane = tid & 63, wid = tid >> 6;
    int tp = lane & 15;
    int kb = (lane >> 4) << 3;
    int P = tp & 1;
    int tb0 = wid * 64;
    const unsigned short* xb = xs + P*CP2 + (tb0 + tp + kb - P);

    f32x4 a0 = {0.f,0.f,0.f,0.f};
    f32x4 a1 = a0, a2 = a0, a3 = a0;
    for (int c = 0; c < NCHAN; c++) {
        bf16x8 af = *(const bf16x8*)(awg + (c*64 + lane)*4);
        const unsigned short* row = xb + c*PB2;
        union Uv { bf16x8 v; unsigned u[4]; };
        Uv B0, B1, B2, B3;
#pragma unroll
        for (int r = 0; r < 4; r++) {
            B0.u[r] = *(const unsigned*)(row + 2*r);
            B1.u[r] = *(const unsigned*)(row + 16 + 2*r);
            B2.u[r] = *(const unsigned*)(row + 32 + 2*r);
            B3.u[r] = *(const unsigned*)(row + 48 + 2*r);
        }
        a0 = __builtin_amdgcn_mfma_f32_16x16x32_bf16(af, B0.v, a0, 0, 0, 0);
        a1 = __builtin_amdgcn_mfma_f32_16x16x32_bf16(af, B1.v, a1, 0, 0, 0);
        a2 = __builtin_amdgcn_mfma_f32_16x16x32_bf16(af, B2.v, a2, 0, 0, 0);
        a3 = __builtin_amdgcn_mfma_f32_16x16x32_bf16(af, B3.v, a3, 0, 0, 0);
    }

    {
        int c2b = (lane >> 4) * 4;
        float bc[4];
#pragma unroll
        for (int r = 0; r < 4; r++) bc[r] = consts[C_BC2 + c2b + r];
#pragma unroll
        for (int r = 0; r < 4; r++) {
            float v;
            v = a0[r] + bc[r]; sq[(c2b+r)*SQP2 + tb0 + tp +  0] = v*v;
            v = a1[r] + bc[r]; sq[(c2b+r)*SQP2 + tb0 + tp + 16] = v*v;
            v = a2[r] + bc[r]; sq[(c2b+r)*SQP2 + tb0 + tp + 32] = v*v;
            v = a3[r] + bc[r]; sq[(c2b+r)*SQP2 + tb0 + tp + 48] = v*v;
        }
    }
    __syncthreads();

    if (tid < 160) {
        int c2 = tid / 10, ch = tid % 10;
        const float* s = &sq[c2*SQP2 + ch*25];
        float acc2 = 0.f;
#pragma unroll
        for (int i = 0; i < 25; i++) acc2 += s[i];
        chnk[(b*16 + c2)*40 + q*10 + ch] = acc2;
    }
}

__global__ __launch_bounds__(256, 3)
void k_front(const float* __restrict__ x,
             const float* __restrict__ consts,
             const float* __restrict__ w_sp1b, const float* __restrict__ b_sp1b,
             const float* __restrict__ g_bn4, const float* __restrict__ b_bn4,
             float* __restrict__ seq, float* __restrict__ chnk)
{
    __shared__ __align__(16) float smem[FRONT_SM];
    int bid = blockIdx.x;
    if (bid < BBATCH*4) {
        b1mm_body(smem, bid, x, consts, w_sp1b, b_sp1b, g_bn4, b_bn4, seq);
    } else {
        b2mm_body(smem, bid - BBATCH*4, x, consts, chnk);
    }
}

// ---------------- SSM scan: 4 batches per block (32 blocks) ----------
__global__ __launch_bounds__(64, 1)
void k_ssm(const float* __restrict__ seq, const float* __restrict__ chnk,
           const float* __restrict__ Amat, const float* __restrict__ Bmat,
           float* __restrict__ stbuf)
{
    int tid = threadIdx.x;          // 64
    int j = tid & 15;
    int b = blockIdx.x * 4 + (tid >> 4);

    float Acol[16], Brow[16];
#pragma unroll
    for (int i = 0; i < 16; i++) {
        Acol[i] = Amat[i*16 + j];
        Brow[i] = Bmat[j*16 + i];
    }

    float xv[LSEQ];
#pragma unroll
    for (int l = 0; l < 31; l++) xv[l] = seq[(b*LSEQ + l)*16 + j];
    {
        float cp[40];
        const float4* cpp = (const float4*)(chnk + (b*16 + j)*40);
#pragma unroll
        for (int i = 0; i < 10; i++) {
            float4 v = cpp[i];
            cp[4*i]=v.x; cp[4*i+1]=v.y; cp[4*i+2]=v.z; cp[4*i+3]=v.w;
        }
#pragma unroll
        for (int w = 0; w < 38; w++) {
            float m = (cp[w] + cp[w+1] + cp[w+2]) * (1.f/75.f);
            xv[31 + w] = logf(fmaxf(m, 1e-6f));
        }
    }

#pragma unroll
    for (int l = 0; l < LSEQ; l++) {
        float u;
        MV16(u, xv[l], Brow);
        xv[l] = u;
    }

    float st = 0.f;
#pragma unroll
    for (int l = 0; l < LSEQ; l++) {
        float nv;
        MV16(nv, st, Acol);
        st = nv + xv[l];
        stbuf[(l*BBATCH + b)*16 + j] = st;
    }
}

// ---------------- transformer layer: all weights LDS-staged ---------------
#define KVS2 38
#define F1S 17
__global__ __launch_bounds__(256, 2)
void k_tfl(const float* __restrict__ hin, const float* __restrict__ Cmat, int applyC,
           const float* __restrict__ qw, const float* __restrict__ qb,
           const float* __restrict__ pw, const float* __restrict__ pb,
           const float* __restrict__ f1w, const float* __restrict__ f1b,
           const float* __restrict__ f2w, const float* __restrict__ f2b,
           const float* __restrict__ g1, const float* __restrict__ b1,
           const float* __restrict__ g2, const float* __restrict__ b2,
           float* __restrict__ hout, float* __restrict__ fout, int writeFinal)
{
    __shared__ __align__(16) float sm[2176 + 128*KVS2 + 576 + 544 + 7*544
                                      + 64*F1S + 1024 + 64
                                      + 256 + 768 + 48 + 256 + 16 + 64];
    float* h_l  = sm;                        // [128][17]
    float* kvq  = sm + 2176;                 // [128][38]
    float* qbuf = sm + 2176 + 128*KVS2;      // [32][18]
    float* olds = qbuf + 576;                // [32][17]
    float* ffp  = olds + 544;                // [7][32][17]
    float* f1l  = ffp + 7*544;               // [64][17]
    float* f2l  = f1l + 64*F1S;              // [1024]
    float* f1bl = f2l + 1024;                // [64]
    float* cml  = f1bl + 64;                 // [256]
    float* qwl  = cml + 256;                 // [768]
    float* qbl  = qwl + 768;                 // [48]
    float* pwl  = qbl + 48;                  // [256]
    float* pbl  = pwl + 256;                 // [16]
    float* lnl  = pbl + 16;                  // [64]: g1,b1,g2,b2

    int tid = threadIdx.x;
    int rl = tid >> 3, hh = tid & 7;
    int n = blockIdx.x >> 2, q2 = blockIdx.x & 3;
    int s = q2*32 + rl;

    // ---- stage ALL weights (coalesced; removes cold scalar-cache misses) ----
    for (int i = tid; i < 1024; i += 256) {
        f1l[(i >> 4)*F1S + (i & 15)] = f1w[i];
        f2l[i] = f2w[i];
    }
    for (int i = tid; i < 768; i += 256) qwl[i] = qw[i];
    if (tid < 256) { cml[tid] = Cmat[tid]; pwl[tid] = pw[tid]; }
    if (tid < 64) f1bl[tid] = f1b[tid];
    if (tid < 48) qbl[tid] = qb[tid];
    if (tid < 16) {
        pbl[tid] = pb[tid];
        lnl[tid] = g1[tid]; lnl[16 + tid] = b1[tid];
        lnl[32 + tid] = g2[tid]; lnl[48 + tid] = b2[tid];
    }
    __syncthreads();

    // ---- phase A: input rows (all 128), n-major coalesced ----
    {
        int r = tid >> 1, qd = tid & 1;
        if (applyC) {
            const float4* fr = (const float4*)(hin + (n*BBATCH + r)*16);
            float rv[16];
#pragma unroll
            for (int i = 0; i < 4; i++) {
                float4 a = fr[i];
                rv[4*i]=a.x; rv[4*i+1]=a.y; rv[4*i+2]=a.z; rv[4*i+3]=a.w;
            }
#pragma unroll
            for (int cq = 0; cq < 8; cq++) {
                int c = 8*qd + cq;
                float sum = 0.f;
#pragma unroll
                for (int i = 0; i < 16; i++) sum += rv[i] * cml[c*16 + i];
                h_l[r*17 + c] = sum;
            }
        } else {
            const float4* sr = (const float4*)(hin + (n*BBATCH + r)*16 + qd*8);
            float4 a0 = sr[0];
            float4 a1 = sr[1];
            h_l[r*17 + qd*8 + 0] = a0.x; h_l[r*17 + qd*8 + 1] = a0.y;
            h_l[r*17 + qd*8 + 2] = a0.z; h_l[r*17 + qd*8 + 3] = a0.w;
            h_l[r*17 + qd*8 + 4] = a1.x; h_l[r*17 + qd*8 + 5] = a1.y;
            h_l[r*17 + qd*8 + 6] = a1.z; h_l[r*17 + qd*8 + 7] = a1.w;
        }
    }
    __syncthreads();

    // ---- phase B: K,V for all 128 rows; Q for own 32 rows ----
    {
        int r2 = tid & 127;
        int ob = 16 + (tid >> 7) * 16;
        float hv[16];
#pragma unroll
        for (int c = 0; c < 16; c++) hv[c] = h_l[r2*17 + c];
#pragma unroll
        for (int oq = 0; oq < 16; oq++) {
            int o = ob + oq;
            float sum = qbl[o];
#pragma unroll
            for (int c = 0; c < 16; c++) sum += qwl[o*16 + c] * hv[c];
            kvq[r2*KVS2 + (o - 16)] = sum;
        }
        if (tid < 32) {
            int sr = q2*32 + tid;
            float hq[16];
#pragma unroll
            for (int c = 0; c < 16; c++) hq[c] = h_l[sr*17 + c];
#pragma unroll
            for (int o = 0; o < 16; o++) {
                float sum = qbl[o];
#pragma unroll
                for (int c = 0; c < 16; c++) sum += qwl[o*16 + c] * hq[c];
                qbuf[tid*18 + o] = sum;
            }
        }
    }
    __syncthreads();

    // ---- phase C: attention, two-pass softmax with immediate offsets ----
    {
        const float SC = 1.0201941311775597f;   // (1/sqrt(2)) * log2(e)
        float q0 = qbuf[rl*18 + 2*hh] * SC;
        float q1 = qbuf[rl*18 + 2*hh + 1] * SC;
        const float* kbase = &kvq[2*hh];
        float m0 = -1e30f, m1 = -1e30f, m2 = -1e30f, m3 = -1e30f;
#pragma unroll
        for (int tb = 0; tb < 128; tb += 4) {
            float2 k0 = *(const float2*)&kbase[(tb+0)*KVS2];
            float2 k1 = *(const float2*)&kbase[(tb+1)*KVS2];
            float2 k2 = *(const float2*)&kbase[(tb+2)*KVS2];
            float2 k3 = *(const float2*)&kbase[(tb+3)*KVS2];
            m0 = fmaxf(m0, q0*k0.x + q1*k0.y);
            m1 = fmaxf(m1, q0*k1.x + q1*k1.y);
            m2 = fmaxf(m2, q0*k2.x + q1*k2.y);
            m3 = fmaxf(m3, q0*k3.x + q1*k3.y);
        }
        float M = fmaxf(fmaxf(m0, m1), fmaxf(m2, m3));
        float su0 = 0.f, su1 = 0.f, su2 = 0.f, su3 = 0.f;
        float av0 = 0.f, av1 = 0.f, av2 = 0.f, av3 = 0.f;
        float bv0 = 0.f, bv1 = 0.f, bv2 = 0.f, bv3 = 0.f;
#pragma unroll
        for (int tb = 0; tb < 128; tb += 4) {
            float2 k0 = *(const float2*)&kbase[(tb+0)*KVS2];
            float2 k1 = *(const float2*)&kbase[(tb+1)*KVS2];
            float2 k2 = *(const float2*)&kbase[(tb+2)*KVS2];
            float2 k3 = *(const float2*)&kbase[(tb+3)*KVS2];
            float2 v0 = *(const float2*)&kbase[(tb+0)*KVS2 + 16];
            float2 v1 = *(const float2*)&kbase[(tb+1)*KVS2 + 16];
            float2 v2 = *(const float2*)&kbase[(tb+2)*KVS2 + 16];
            float2 v3 = *(const float2*)&kbase[(tb+3)*KVS2 + 16];
            float e0 = exp2f(q0*k0.x + q1*k0.y - M);
            float e1 = exp2f(q0*k1.x + q1*k1.y - M);
            float e2 = exp2f(q0*k2.x + q1*k2.y - M);
            float e3 = exp2f(q0*k3.x + q1*k3.y - M);
            su0 += e0; av0 += e0*v0.x; bv0 += e0*v0.y;
            su1 += e1; av1 += e1*v1.x; bv1 += e1*v1.y;
            su2 += e2; av2 += e2*v2.x; bv2 += e2*v2.y;
            su3 += e3; av3 += e3*v3.x; bv3 += e3*v3.y;
        }
        float su = (su0 + su1) + (su2 + su3);
        float av = (av0 + av1) + (av2 + av3);
        float bv = (bv0 + bv1) + (bv2 + bv3);
        float inv = 1.f / su;
        olds[rl*17 + 2*hh + 0] = av * inv;
        olds[rl*17 + 2*hh + 1] = bv * inv;
    }
    __syncthreads();

    // ---- phase D: proj+LN1 redundant per hh; FF slice hh (LDS weights) ----
    {
        float rv[16], ov[16];
#pragma unroll
        for (int c = 0; c < 16; c++) { rv[c] = h_l[s*17 + c]; ov[c] = olds[rl*17 + c]; }
        float h1[16];
#pragma unroll
        for (int c = 0; c < 16; c++) {
            float p = pbl[c];
#pragma unroll
            for (int j = 0; j < 16; j++) p += pwl[c*16 + j] * ov[j];
            h1[c] = rv[c] + p;
        }
        float mn = 0.f;
#pragma unroll
        for (int c = 0; c < 16; c++) mn += h1[c];
        mn *= (1.f/16.f);
        float var = 0.f;
#pragma unroll
        for (int c = 0; c < 16; c++) { float d = h1[c] - mn; var += d*d; }
        var *= (1.f/16.f);
        float rs = rsqrtf(var + 1e-5f);
        float y[16];
#pragma unroll
        for (int c = 0; c < 16; c++) y[c] = (h1[c] - mn)*rs*lnl[c] + lnl[16 + c];

        float t2[16];
#pragma unroll
        for (int c = 0; c < 16; c++) t2[c] = (hh == 0) ? f2b[c] : 0.f;
#pragma unroll
        for (int uq = 0; uq < 8; uq++) {
            int u = 8*hh + uq;
            float sv = f1bl[u];
#pragma unroll
            for (int c = 0; c < 16; c++) sv += f1l[u*F1S + c] * y[c];
            sv = fmaxf(sv, 0.f);
#pragma unroll
            for (int c = 0; c < 16; c++) t2[c] += f2l[c*64 + u] * sv;
        }
        if (hh) {
#pragma unroll
            for (int c = 0; c < 16; c++) ffp[(hh-1)*544 + rl*17 + c] = t2[c];
        }
        __syncthreads();
        if (hh == 0) {
#pragma unroll
            for (int k = 0; k < 7; k++)
#pragma unroll
                for (int c = 0; c < 16; c++) t2[c] += ffp[k*544 + rl*17 + c];
            float h2[16];
#pragma unroll
            for (int c = 0; c < 16; c++) h2[c] = y[c] + t2[c];
            mn = 0.f;
#pragma unroll
            for (int c = 0; c < 16; c++) mn += h2[c];
            mn *= (1.f/16.f);
            var = 0.f;
#pragma unroll
            for (int c = 0; c < 16; c++) { float d = h2[c] - mn; var += d*d; }
            var *= (1.f/16.f);
            rs = rsqrtf(var + 1e-5f);
            if (writeFinal) {
#pragma unroll
                for (int c = 0; c < 16; c++)
                    fout[(s*16 + c)*LSEQ + n] = (h2[c] - mn)*rs*lnl[32 + c] + lnl[48 + c];
            } else {
                float z[16];
#pragma unroll
                for (int c = 0; c < 16; c++) z[c] = (h2[c] - mn)*rs*lnl[32 + c] + lnl[48 + c];
                float* hp = hout + (n*BBATCH + s)*16;
#pragma unroll
                for (int i = 0; i < 4; i++)
                    *(float4*)&hp[4*i] = make_float4(z[4*i], z[4*i+1], z[4*i+2], z[4*i+3]);
            }
        }
    }
}

extern "C" void kernel_launch(void* const* d_in, const int* in_sizes, int n_in,
                              void* d_out, int out_size, void* d_ws, size_t ws_size,
                              hipStream_t stream)
{
    const float* x       = (const float*)d_in[0];
    const float* w_spec1 = (const float*)d_in[1];
    const float* b_spec1 = (const float*)d_in[2];
    const float* w_spec2 = (const float*)d_in[3];
    const float* b_spec2 = (const float*)d_in[4];
    const float* g_bn1   = (const float*)d_in[5];
    const float* b_bn1   = (const float*)d_in[6];
    const float* g_bn2   = (const float*)d_in[7];
    const float* b_bn2   = (const float*)d_in[8];
    const float* w_sp1a  = (const float*)d_in[9];
    const float* g_bn3   = (const float*)d_in[10];
    const float* b_bn3   = (const float*)d_in[11];
    const float* w_sp1b  = (const float*)d_in[12];
    const float* b_sp1b  = (const float*)d_in[13];
    const float* g_bn4   = (const float*)d_in[14];
    const float* b_bn4   = (const float*)d_in[15];
    const float* w_sp2   = (const float*)d_in[16];
    const float* b_sp2   = (const float*)d_in[17];
    const float* g_bn5   = (const float*)d_in[18];
    const float* b_bn5   = (const float*)d_in[19];
    const float* Amat    = (const float*)d_in[20];
    const float* Bmat    = (const float*)d_in[21];
    const float* Cmat    = (const float*)d_in[22];
    const float* qkv_w   = (const float*)d_in[23];
    const float* qkv_b   = (const float*)d_in[24];
    const float* proj_w  = (const float*)d_in[25];
    const float* proj_b  = (const float*)d_in[26];
    const float* ff1_w   = (const float*)d_in[27];
    const float* ff1_b   = (const float*)d_in[28];
    const float* ff2_w   = (const float*)d_in[29];
    const float* ff2_b   = (const float*)d_in[30];
    const float* ln1_g   = (const float*)d_in[31];
    const float* ln1_b   = (const float*)d_in[32];
    const float* ln2_g   = (const float*)d_in[33];
    const float* ln2_b   = (const float*)d_in[34];

    float* ws  = (float*)d_ws;
    float* out = (float*)d_out;

    float* consts = ws + OFF_CONST;
    float* chnk   = ws + OFF_CHNK;
    float* seq    = ws + OFF_SEQ;
    float* stbuf  = ws + OFF_STB;
    float* hbuf   = ws + OFF_HBUF;

    k_setup<<<24, 256, 0, stream>>>(w_sp1a, b_spec1, g_bn1, b_bn1, g_bn3, b_bn3,
                                    w_spec2, b_spec2, g_bn2, b_bn2,
                                    w_sp2, b_sp2, g_bn5, b_bn5, w_spec1, consts);
    k_front<<<BBATCH*4 + BBATCH*4, 256, 0, stream>>>(x, consts,
        w_sp1b, b_sp1b, g_bn4, b_bn4, seq, chnk);
    k_ssm<<<BBATCH/4, 64, 0, stream>>>(seq, chnk, Amat, Bmat, stbuf);

    k_tfl<<<LSEQ*4, 256, 0, stream>>>(stbuf, Cmat, 1,
        qkv_w, qkv_b, proj_w, proj_b, ff1_w, ff1_b, ff2_w, ff2_b,
        ln1_g, ln1_b, ln2_g, ln2_b, hbuf, out, 0);
    k_tfl<<<LSEQ*4, 256, 0, stream>>>(hbuf, Cmat, 0,
        qkv_w + 768, qkv_b + 48, proj_w + 256, proj_b + 16,
        ff1_w + 1024, ff1_b + 64, ff2_w + 1024, ff2_b + 16,
        ln1_g + 16, ln1_b + 16, ln2_g + 16, ln2_b + 16, hbuf, out, 1);
}

// Round 25
// 116.098 us; speedup vs baseline: 1.2967x; 1.2967x over previous
//
#include <hip/hip_runtime.h>
#include <hip/hip_bf16.h>
#include <math.h>

// Problem dims
#define BBATCH 128
#define NCHAN  22
#define TLEN   1000
#define F1C    8
#define F2C    16
#define L1W    31
#define L2W    38
#define LSEQ   69
#define EDIM   16
#define NHEAD  8
#define FFDIM  64

// const block offsets (floats within ws)
#define C_SA   0
#define C_BA   16
#define C_BC2  32
#define C_AW   4144                     // packed bf16 A-frags branch2: 22*64*4 u32
#define C_AW1  (C_AW + 5632)            // branch1 A-frags: 22*4*64*4 u32
#define C_TOTAL (C_AW1 + 22528)

// ws layout (floats)
#define OFF_CONST 0
#define OFF_CHNK  40960
#define OFF_SEQ   (OFF_CHNK + 81920)
#define OFF_STB   (OFF_SEQ + 141312)
#define OFF_HBUF  (OFF_STB + 141312)

typedef __attribute__((ext_vector_type(8))) short bf16x8;
typedef __attribute__((ext_vector_type(4))) float f32x4;

static __device__ __forceinline__ unsigned short f2bf(float f) {
    unsigned u = __float_as_uint(f);
    unsigned r = (u + 0x7FFFu + ((u >> 16) & 1u)) >> 16;    // RNE
    return (unsigned short)r;
}

// broadcast-from-lane-i within 16-lane groups (wave64-safe)
#define SWZ(v, imm) __int_as_float(__builtin_amdgcn_ds_swizzle(__float_as_int(v), imm))
#define MV16(dst, sv, W) do { \
    float p0=SWZ(sv,0x010)*W[0],  p1=SWZ(sv,0x030)*W[1],  \
          p2=SWZ(sv,0x050)*W[2],  p3=SWZ(sv,0x070)*W[3],  \
          p4=SWZ(sv,0x090)*W[4],  p5=SWZ(sv,0x0B0)*W[5],  \
          p6=SWZ(sv,0x0D0)*W[6],  p7=SWZ(sv,0x0F0)*W[7],  \
          p8=SWZ(sv,0x110)*W[8],  p9=SWZ(sv,0x130)*W[9],  \
          p10=SWZ(sv,0x150)*W[10],p11=SWZ(sv,0x170)*W[11],\
          p12=SWZ(sv,0x190)*W[12],p13=SWZ(sv,0x1B0)*W[13],\
          p14=SWZ(sv,0x1D0)*W[14],p15=SWZ(sv,0x1F0)*W[15];\
    dst = (((p0+p1)+(p2+p3))+((p4+p5)+(p6+p7))) + (((p8+p9)+(p10+p11))+((p12+p13)+(p14+p15))); \
} while(0)

// ---------------- setup: parallelized across 24 blocks -------------------
__global__ void k_setup(const float* __restrict__ wsp1a, const float* __restrict__ b_spec1,
                        const float* __restrict__ g_bn1, const float* __restrict__ b_bn1,
                        const float* __restrict__ g_bn3, const float* __restrict__ b_bn3,
                        const float* __restrict__ w_spec2, const float* __restrict__ b_spec2,
                        const float* __restrict__ g_bn2, const float* __restrict__ b_bn2,
                        const float* __restrict__ w_sp2, const float* __restrict__ b_sp2,
                        const float* __restrict__ g_bn5, const float* __restrict__ b_bn5,
                        const float* __restrict__ w_spec1,
                        float* __restrict__ consts)
{
    int tid = threadIdx.x;
    int gb = blockIdx.x;
    int NG = gridDim.x;
    int gid = gb*256 + tid;
    float rbn = rsqrtf(1.0f + 1e-5f);
    if (gb == 0 && tid < 16) {
        int c2 = tid, c1 = c2 >> 1;
        float wsum = 0.f;
        for (int h = 0; h < NCHAN; h++) wsum += wsp1a[c2*NCHAN + h];
        float s1b = g_bn1[c1] * rbn;
        float s3  = g_bn3[c2] * rbn;
        float C1  = (s1b * b_spec1[c1] + b_bn1[c1]) * wsum;
        consts[C_SA + c2] = s3 * s1b;
        consts[C_BA + c2] = s3 * C1 + b_bn3[c2];
        float s5 = g_bn5[c2] * rbn;
        float acc = b_sp2[c2];
        for (int cc = 0; cc < F1C; cc++) {
            float s2b = g_bn2[cc] * rbn;
            float cb  = s2b * b_spec2[cc] + b_bn2[cc];
            float wsh = 0.f;
            for (int h = 0; h < NCHAN; h++) wsh += w_sp2[(c2*F1C + cc)*NCHAN + h];
            acc += wsh * cb;
        }
        consts[C_BC2 + c2] = s5 * acc + b_bn5[c2];
    }
    unsigned* aw = (unsigned*)&consts[C_AW];
    for (int idx = gid; idx < 22*64*4; idx += 256*NG) {
        int r = idx & 3;
        int l = (idx >> 2) & 63;
        int c = idx >> 8;
        int m = l & 15;
        int k0 = ((l >> 4) << 3) + 2*r;
        float s5 = g_bn5[m] * rbn;
        float w0 = 0.f, w1 = 0.f;
        for (int cc = 0; cc < F1C; cc++) {
            float f = w_sp2[(m*F1C + cc)*NCHAN + c] * (g_bn2[cc] * rbn);
            if (k0 < 30)     w0 += f * w_spec2[cc*30 + k0];
            if (k0 + 1 < 30) w1 += f * w_spec2[cc*30 + k0 + 1];
        }
        w0 *= s5; w1 *= s5;
        aw[idx] = (unsigned)f2bf(w0) | ((unsigned)f2bf(w1) << 16);
    }
    unsigned* aw1 = (unsigned*)&consts[C_AW1];
    for (int idx = gid; idx < 22*4*64*4; idx += 256*NG) {
        int r = idx & 3;
        int l = (idx >> 2) & 63;
        int kk = (idx >> 8) & 3;
        int c = idx >> 10;
        int m = l & 15;
        int klocal = ((l >> 4) << 3) + 2*r;
        int tap0 = kk*32 + klocal;
        float sa = (g_bn3[m] * rbn) * (g_bn1[m >> 1] * rbn);
        float base = sa * wsp1a[m*NCHAN + c];
        float w0 = (tap0     < 125) ? base * w_spec1[(m >> 1)*125 + tap0]     : 0.f;
        float w1 = (tap0 + 1 < 125) ? base * w_spec1[(m >> 1)*125 + tap0 + 1] : 0.f;
        aw1[idx] = (unsigned)f2bf(w0) | ((unsigned)f2bf(w1) << 16);
    }
}

// ---------------- merged front: b1mm (bid<512) + b2mm (bid>=512) --------
// Parity copies padded +16 shorts so copy offset is not 0 mod 128 bytes.
#define PB1 384
#define NW1 (NCHAN*PB1)          // 8448 shorts
#define CP1 (NW1 + 16)           // padded copy stride
#define PS1 257
#define PB2 288
#define NW2 (NCHAN*PB2)          // 6336 shorts
#define CP2 (NW2 + 16)
#define SQP2 257
#define FRONT_SM 12568           // (2*NW1+16)/2 = 8456 fl + 16*257 = 4112 fl

__device__ __forceinline__ void b1mm_body(float* smem, int bid,
    const float* __restrict__ x, const float* __restrict__ consts,
    const float* __restrict__ w_sp1b, const float* __restrict__ b_sp1b,
    const float* __restrict__ g_bn4, const float* __restrict__ b_bn4,
    float* __restrict__ seq)
{
    unsigned short* xs = (unsigned short*)smem;
    float* sq = smem + 8456;
    const uint4* __restrict__ awg = (const uint4*)&consts[C_AW1];
    int q = bid & 3, b = bid >> 2;
    int t0 = q * 256;
    int tid = threadIdx.x;

    for (int idx = tid; idx < NW1; idx += 256) {
        int h = idx / PB1, e = idx - h*PB1;
        int t = t0 - 62 + e;
        const float* xr = x + (b*NCHAN + h)*TLEN;
        float v0 = ((unsigned)t < 1000u && e < 380) ? xr[t] : 0.f;
        float v1 = ((unsigned)(t+1) < 1000u && e < 380) ? xr[t+1] : 0.f;
        xs[idx] = f2bf(v0);
        xs[CP1 + idx] = f2bf(v1);
    }
    __syncthreads();

    int lane = tid & 63, wid = tid >> 6;
    int tp = lane & 15;
    int kb = (lane >> 4) << 3;
    int P = tp & 1;
    int tb0 = wid * 64;
    const unsigned short* xb = xs + P*CP1 + (tb0 + tp + kb - P);

    f32x4 a0 = {0.f,0.f,0.f,0.f};
    f32x4 a1 = a0, a2 = a0, a3 = a0;
    for (int c = 0; c < NCHAN; c++) {
#pragma unroll
        for (int kk = 0; kk < 4; kk++) {
            uint4 au = awg[(c*4 + kk)*64 + lane];
            union Ua { uint4 qv; bf16x8 v; } A; A.qv = au;
            const unsigned short* row = xb + c*PB1 + kk*32;
            union Uv { bf16x8 v; unsigned u[4]; };
            Uv B0, B1, B2, B3;
#pragma unroll
            for (int r = 0; r < 4; r++) {
                B0.u[r] = *(const unsigned*)(row + 2*r);
                B1.u[r] = *(const unsigned*)(row + 16 + 2*r);
                B2.u[r] = *(const unsigned*)(row + 32 + 2*r);
                B3.u[r] = *(const unsigned*)(row + 48 + 2*r);
            }
            a0 = __builtin_amdgcn_mfma_f32_16x16x32_bf16(A.v, B0.v, a0, 0, 0, 0);
            a1 = __builtin_amdgcn_mfma_f32_16x16x32_bf16(A.v, B1.v, a1, 0, 0, 0);
            a2 = __builtin_amdgcn_mfma_f32_16x16x32_bf16(A.v, B2.v, a2, 0, 0, 0);
            a3 = __builtin_amdgcn_mfma_f32_16x16x32_bf16(A.v, B3.v, a3, 0, 0, 0);
        }
    }

    {
        int c2b = (lane >> 4) * 4;
        float ba[4];
#pragma unroll
        for (int r = 0; r < 4; r++) ba[r] = consts[C_BA + c2b + r];
#pragma unroll
        for (int r = 0; r < 4; r++) {
            float v, e;
            v = a0[r] + ba[r]; e = (v > 0.f) ? v : (expf(v) - 1.f);
            sq[(c2b+r)*PS1 + tb0 + tp +  0] = e;
            v = a1[r] + ba[r]; e = (v > 0.f) ? v : (expf(v) - 1.f);
            sq[(c2b+r)*PS1 + tb0 + tp + 16] = e;
            v = a2[r] + ba[r]; e = (v > 0.f) ? v : (expf(v) - 1.f);
            sq[(c2b+r)*PS1 + tb0 + tp + 32] = e;
            v = a3[r] + ba[r]; e = (v > 0.f) ? v : (expf(v) - 1.f);
            sq[(c2b+r)*PS1 + tb0 + tp + 48] = e;
        }
    }
    __syncthreads();

    {
        int u = tid;
        int w = 8*q + (u >> 5);
        float rbn = rsqrtf(1.0f + 1e-5f);
        float hv[16];
#pragma unroll
        for (int c = 0; c < 16; c++) hv[c] = sq[c*PS1 + u];
        float p[16];
#pragma unroll
        for (int c = 0; c < 16; c++) {
            float s = 0.f;
#pragma unroll
            for (int j = 0; j < 16; j++) s += w_sp1b[c*16 + j] * hv[j];
            float sc = g_bn4[c] * rbn;
            float a = sc * (s + b_sp1b[c]) + b_bn4[c];
            float g = (a > 0.f) ? a : (expf(a) - 1.f);
            g += __shfl_xor(g, 1, 64);
            g += __shfl_xor(g, 2, 64);
            g += __shfl_xor(g, 4, 64);
            g += __shfl_xor(g, 8, 64);
            g += __shfl_xor(g, 16, 64);
            p[c] = g;
        }
        if ((u & 31) == 0 && w < L1W) {
            float* sp = &seq[(b*LSEQ + w)*16];
#pragma unroll
            for (int i = 0; i < 4; i++)
                *(float4*)&sp[4*i] = make_float4(p[4*i]*(1.f/32.f), p[4*i+1]*(1.f/32.f),
                                                 p[4*i+2]*(1.f/32.f), p[4*i+3]*(1.f/32.f));
        }
    }
}

__device__ __forceinline__ void b2mm_body(float* smem, int bid,
    const float* __restrict__ x, const float* __restrict__ consts,
    float* __restrict__ chnk)
{
    unsigned short* xs = (unsigned short*)smem;
    float* sq = smem + 6344;     // (2*NW2+16)/2
    const unsigned* __restrict__ awg = (const unsigned*)&consts[C_AW];
    int q = bid & 3, b = bid >> 2;
    int t0 = q * 250;
    int tid = threadIdx.x;

    for (int idx = tid; idx < NW2; idx += 256) {
        int h = idx / PB2, e = idx - h*PB2;
        int t = t0 - 14 + e;
        const float* xr = x + (b*NCHAN + h)*TLEN;
        float v0 = ((unsigned)t < 1000u) ? xr[t] : 0.f;
        float v1 = ((unsigned)(t+1) < 1000u) ? xr[t+1] : 0.f;
        xs[idx] = f2bf(v0);
        xs[CP2 + idx] = f2bf(v1);
    }
    __syncthreads();

    int lane = tid & 63, wid = tid >> 6;
    int tp = lane & 15;
    int kb = (lane >> 4) << 3;
    int P = tp & 1;
    int tb0 = wid * 64;
    const unsigned short* xb = xs + P*CP2 + (tb0 + tp + kb - P);

    f32x4 a0 = {0.f,0.f,0.f,0.f};
    f32x4 a1 = a0, a2 = a0, a3 = a0;
    for (int c = 0; c < NCHAN; c++) {
        bf16x8 af = *(const bf16x8*)(awg + (c*64 + lane)*4);
        const unsigned short* row = xb + c*PB2;
        union Uv { bf16x8 v; unsigned u[4]; };
        Uv B0, B1, B2, B3;
#pragma unroll
        for (int r = 0; r < 4; r++) {
            B0.u[r] = *(const unsigned*)(row + 2*r);
            B1.u[r] = *(const unsigned*)(row + 16 + 2*r);
            B2.u[r] = *(const unsigned*)(row + 32 + 2*r);
            B3.u[r] = *(const unsigned*)(row + 48 + 2*r);
        }
        a0 = __builtin_amdgcn_mfma_f32_16x16x32_bf16(af, B0.v, a0, 0, 0, 0);
        a1 = __builtin_amdgcn_mfma_f32_16x16x32_bf16(af, B1.v, a1, 0, 0, 0);
        a2 = __builtin_amdgcn_mfma_f32_16x16x32_bf16(af, B2.v, a2, 0, 0, 0);
        a3 = __builtin_amdgcn_mfma_f32_16x16x32_bf16(af, B3.v, a3, 0, 0, 0);
    }

    {
        int c2b = (lane >> 4) * 4;
        float bc[4];
#pragma unroll
        for (int r = 0; r < 4; r++) bc[r] = consts[C_BC2 + c2b + r];
#pragma unroll
        for (int r = 0; r < 4; r++) {
            float v;
            v = a0[r] + bc[r]; sq[(c2b+r)*SQP2 + tb0 + tp +  0] = v*v;
            v = a1[r] + bc[r]; sq[(c2b+r)*SQP2 + tb0 + tp + 16] = v*v;
            v = a2[r] + bc[r]; sq[(c2b+r)*SQP2 + tb0 + tp + 32] = v*v;
            v = a3[r] + bc[r]; sq[(c2b+r)*SQP2 + tb0 + tp + 48] = v*v;
        }
    }
    __syncthreads();

    if (tid < 160) {
        int c2 = tid / 10, ch = tid % 10;
        const float* s = &sq[c2*SQP2 + ch*25];
        float acc2 = 0.f;
#pragma unroll
        for (int i = 0; i < 25; i++) acc2 += s[i];
        chnk[(b*16 + c2)*40 + q*10 + ch] = acc2;
    }
}

__global__ __launch_bounds__(256, 3)
void k_front(const float* __restrict__ x,
             const float* __restrict__ consts,
             const float* __restrict__ w_sp1b, const float* __restrict__ b_sp1b,
             const float* __restrict__ g_bn4, const float* __restrict__ b_bn4,
             float* __restrict__ seq, float* __restrict__ chnk)
{
    __shared__ __align__(16) float smem[FRONT_SM];
    int bid = blockIdx.x;
    if (bid < BBATCH*4) {
        b1mm_body(smem, bid, x, consts, w_sp1b, b_sp1b, g_bn4, b_bn4, seq);
    } else {
        b2mm_body(smem, bid - BBATCH*4, x, consts, chnk);
    }
}

// ---------------- SSM scan: 4 batches per block (32 blocks) ----------
__global__ __launch_bounds__(64, 1)
void k_ssm(const float* __restrict__ seq, const float* __restrict__ chnk,
           const float* __restrict__ Amat, const float* __restrict__ Bmat,
           float* __restrict__ stbuf)
{
    int tid = threadIdx.x;          // 64
    int j = tid & 15;
    int b = blockIdx.x * 4 + (tid >> 4);

    float Acol[16], Brow[16];
#pragma unroll
    for (int i = 0; i < 16; i++) {
        Acol[i] = Amat[i*16 + j];
        Brow[i] = Bmat[j*16 + i];
    }

    float xv[LSEQ];
#pragma unroll
    for (int l = 0; l < 31; l++) xv[l] = seq[(b*LSEQ + l)*16 + j];
    {
        float cp[40];
        const float4* cpp = (const float4*)(chnk + (b*16 + j)*40);
#pragma unroll
        for (int i = 0; i < 10; i++) {
            float4 v = cpp[i];
            cp[4*i]=v.x; cp[4*i+1]=v.y; cp[4*i+2]=v.z; cp[4*i+3]=v.w;
        }
#pragma unroll
        for (int w = 0; w < 38; w++) {
            float m = (cp[w] + cp[w+1] + cp[w+2]) * (1.f/75.f);
            xv[31 + w] = logf(fmaxf(m, 1e-6f));
        }
    }

#pragma unroll
    for (int l = 0; l < LSEQ; l++) {
        float u;
        MV16(u, xv[l], Brow);
        xv[l] = u;
    }

    float st = 0.f;
#pragma unroll
    for (int l = 0; l < LSEQ; l++) {
        float nv;
        MV16(nv, st, Acol);
        st = nv + xv[l];
        stbuf[(l*BBATCH + b)*16 + j] = st;
    }
}

// ---------------- transformer layer: two-pass softmax, padded f1l ---------
#define KVS2 38
#define F1S 17
__global__ __launch_bounds__(256, 2)
void k_tfl(const float* __restrict__ hin, const float* __restrict__ Cmat, int applyC,
           const float* __restrict__ qw, const float* __restrict__ qb,
           const float* __restrict__ pw, const float* __restrict__ pb,
           const float* __restrict__ f1w, const float* __restrict__ f1b,
           const float* __restrict__ f2w, const float* __restrict__ f2b,
           const float* __restrict__ g1, const float* __restrict__ b1,
           const float* __restrict__ g2, const float* __restrict__ b2,
           float* __restrict__ hout, float* __restrict__ fout, int writeFinal)
{
    __shared__ __align__(16) float sm[2176 + 128*KVS2 + 576 + 544 + 7*544 + 64*F1S + 1024 + 64];
    float* h_l  = sm;                        // [128][17]
    float* kvq  = sm + 2176;                 // [128][38]: K 0..15, V 16..31
    float* qbuf = sm + 2176 + 128*KVS2;      // [32][18]
    float* olds = qbuf + 576;                // [32][17]
    float* ffp  = olds + 544;                // [7][32][17]
    float* f1l  = ffp + 7*544;               // [64][17] padded
    float* f2l  = f1l + 64*F1S;              // [1024]
    float* f1bl = f2l + 1024;                // [64]

    int tid = threadIdx.x;
    int rl = tid >> 3, hh = tid & 7;
    int n = blockIdx.x >> 2, q2 = blockIdx.x & 3;
    int s = q2*32 + rl;

    for (int i = tid; i < 1024; i += 256) {
        f1l[(i >> 4)*F1S + (i & 15)] = f1w[i];
        f2l[i] = f2w[i];
    }
    if (tid < 64) f1bl[tid] = f1b[tid];

    // ---- phase A: input rows (all 128), n-major coalesced ----
    {
        int r = tid >> 1, qd = tid & 1;
        if (applyC) {
            const float4* fr = (const float4*)(hin + (n*BBATCH + r)*16);
            float rv[16];
#pragma unroll
            for (int i = 0; i < 4; i++) {
                float4 a = fr[i];
                rv[4*i]=a.x; rv[4*i+1]=a.y; rv[4*i+2]=a.z; rv[4*i+3]=a.w;
            }
#pragma unroll
            for (int cq = 0; cq < 8; cq++) {
                int c = 8*qd + cq;
                float sum = 0.f;
#pragma unroll
                for (int i = 0; i < 16; i++) sum += rv[i] * Cmat[c*16 + i];
                h_l[r*17 + c] = sum;
            }
        } else {
            const float4* sr = (const float4*)(hin + (n*BBATCH + r)*16 + qd*8);
            float4 a0 = sr[0];
            float4 a1 = sr[1];
            h_l[r*17 + qd*8 + 0] = a0.x; h_l[r*17 + qd*8 + 1] = a0.y;
            h_l[r*17 + qd*8 + 2] = a0.z; h_l[r*17 + qd*8 + 3] = a0.w;
            h_l[r*17 + qd*8 + 4] = a1.x; h_l[r*17 + qd*8 + 5] = a1.y;
            h_l[r*17 + qd*8 + 6] = a1.z; h_l[r*17 + qd*8 + 7] = a1.w;
        }
    }
    __syncthreads();

    // ---- phase B: K,V for all 128 rows; Q for own 32 rows ----
    {
        int r2 = tid & 127;
        int ob = 16 + (tid >> 7) * 16;
        float hv[16];
#pragma unroll
        for (int c = 0; c < 16; c++) hv[c] = h_l[r2*17 + c];
#pragma unroll
        for (int oq = 0; oq < 16; oq++) {
            int o = ob + oq;
            float sum = qb[o];
#pragma unroll
            for (int c = 0; c < 16; c++) sum += qw[o*16 + c] * hv[c];
            kvq[r2*KVS2 + (o - 16)] = sum;
        }
        if (tid < 32) {
            int sr = q2*32 + tid;
            float hq[16];
#pragma unroll
            for (int c = 0; c < 16; c++) hq[c] = h_l[sr*17 + c];
#pragma unroll
            for (int o = 0; o < 16; o++) {
                float sum = qb[o];
#pragma unroll
                for (int c = 0; c < 16; c++) sum += qw[o*16 + c] * hq[c];
                qbuf[tid*18 + o] = sum;
            }
        }
    }
    __syncthreads();

    // ---- phase C: attention, two-pass softmax with immediate offsets ----
    {
        const float SC = 1.0201941311775597f;   // (1/sqrt(2)) * log2(e)
        float q0 = qbuf[rl*18 + 2*hh] * SC;
        float q1 = qbuf[rl*18 + 2*hh + 1] * SC;
        const float* kbase = &kvq[2*hh];
        float m0 = -1e30f, m1 = -1e30f, m2 = -1e30f, m3 = -1e30f;
#pragma unroll
        for (int tb = 0; tb < 128; tb += 4) {
            float2 k0 = *(const float2*)&kbase[(tb+0)*KVS2];
            float2 k1 = *(const float2*)&kbase[(tb+1)*KVS2];
            float2 k2 = *(const float2*)&kbase[(tb+2)*KVS2];
            float2 k3 = *(const float2*)&kbase[(tb+3)*KVS2];
            m0 = fmaxf(m0, q0*k0.x + q1*k0.y);
            m1 = fmaxf(m1, q0*k1.x + q1*k1.y);
            m2 = fmaxf(m2, q0*k2.x + q1*k2.y);
            m3 = fmaxf(m3, q0*k3.x + q1*k3.y);
        }
        float M = fmaxf(fmaxf(m0, m1), fmaxf(m2, m3));
        float su0 = 0.f, su1 = 0.f, su2 = 0.f, su3 = 0.f;
        float av0 = 0.f, av1 = 0.f, av2 = 0.f, av3 = 0.f;
        float bv0 = 0.f, bv1 = 0.f, bv2 = 0.f, bv3 = 0.f;
#pragma unroll
        for (int tb = 0; tb < 128; tb += 4) {
            float2 k0 = *(const float2*)&kbase[(tb+0)*KVS2];
            float2 k1 = *(const float2*)&kbase[(tb+1)*KVS2];
            float2 k2 = *(const float2*)&kbase[(tb+2)*KVS2];
            float2 k3 = *(const float2*)&kbase[(tb+3)*KVS2];
            float2 v0 = *(const float2*)&kbase[(tb+0)*KVS2 + 16];
            float2 v1 = *(const float2*)&kbase[(tb+1)*KVS2 + 16];
            float2 v2 = *(const float2*)&kbase[(tb+2)*KVS2 + 16];
            float2 v3 = *(const float2*)&kbase[(tb+3)*KVS2 + 16];
            float e0 = exp2f(q0*k0.x + q1*k0.y - M);
            float e1 = exp2f(q0*k1.x + q1*k1.y - M);
            float e2 = exp2f(q0*k2.x + q1*k2.y - M);
            float e3 = exp2f(q0*k3.x + q1*k3.y - M);
            su0 += e0; av0 += e0*v0.x; bv0 += e0*v0.y;
            su1 += e1; av1 += e1*v1.x; bv1 += e1*v1.y;
            su2 += e2; av2 += e2*v2.x; bv2 += e2*v2.y;
            su3 += e3; av3 += e3*v3.x; bv3 += e3*v3.y;
        }
        float su = (su0 + su1) + (su2 + su3);
        float av = (av0 + av1) + (av2 + av3);
        float bv = (bv0 + bv1) + (bv2 + bv3);
        float inv = 1.f / su;
        olds[rl*17 + 2*hh + 0] = av * inv;
        olds[rl*17 + 2*hh + 1] = bv * inv;
    }
    __syncthreads();

    // ---- phase D: proj+LN1 redundant per hh; FF slice hh (LDS weights) ----
    {
        float rv[16], ov[16];
#pragma unroll
        for (int c = 0; c < 16; c++) { rv[c] = h_l[s*17 + c]; ov[c] = olds[rl*17 + c]; }
        float h1[16];
#pragma unroll
        for (int c = 0; c < 16; c++) {
            float p = pb[c];
#pragma unroll
            for (int j = 0; j < 16; j++) p += pw[c*16 + j] * ov[j];
            h1[c] = rv[c] + p;
        }
        float mn = 0.f;
#pragma unroll
        for (int c = 0; c < 16; c++) mn += h1[c];
        mn *= (1.f/16.f);
        float var = 0.f;
#pragma unroll
        for (int c = 0; c < 16; c++) { float d = h1[c] - mn; var += d*d; }
        var *= (1.f/16.f);
        float rs = rsqrtf(var + 1e-5f);
        float y[16];
#pragma unroll
        for (int c = 0; c < 16; c++) y[c] = (h1[c] - mn)*rs*g1[c] + b1[c];

        float t2[16];
#pragma unroll
        for (int c = 0; c < 16; c++) t2[c] = (hh == 0) ? f2b[c] : 0.f;
#pragma unroll
        for (int uq = 0; uq < 8; uq++) {
            int u = 8*hh + uq;
            float sv = f1bl[u];
#pragma unroll
            for (int c = 0; c < 16; c++) sv += f1l[u*F1S + c] * y[c];
            sv = fmaxf(sv, 0.f);
#pragma unroll
            for (int c = 0; c < 16; c++) t2[c] += f2l[c*64 + u] * sv;
        }
        if (hh) {
#pragma unroll
            for (int c = 0; c < 16; c++) ffp[(hh-1)*544 + rl*17 + c] = t2[c];
        }
        __syncthreads();
        if (hh == 0) {
#pragma unroll
            for (int k = 0; k < 7; k++)
#pragma unroll
                for (int c = 0; c < 16; c++) t2[c] += ffp[k*544 + rl*17 + c];
            float h2[16];
#pragma unroll
            for (int c = 0; c < 16; c++) h2[c] = y[c] + t2[c];
            mn = 0.f;
#pragma unroll
            for (int c = 0; c < 16; c++) mn += h2[c];
            mn *= (1.f/16.f);
            var = 0.f;
#pragma unroll
            for (int c = 0; c < 16; c++) { float d = h2[c] - mn; var += d*d; }
            var *= (1.f/16.f);
            rs = rsqrtf(var + 1e-5f);
            if (writeFinal) {
#pragma unroll
                for (int c = 0; c < 16; c++)
                    fout[(s*16 + c)*LSEQ + n] = (h2[c] - mn)*rs*g2[c] + b2[c];
            } else {
                float z[16];
#pragma unroll
                for (int c = 0; c < 16; c++) z[c] = (h2[c] - mn)*rs*g2[c] + b2[c];
                float* hp = hout + (n*BBATCH + s)*16;
#pragma unroll
                for (int i = 0; i < 4; i++)
                    *(float4*)&hp[4*i] = make_float4(z[4*i], z[4*i+1], z[4*i+2], z[4*i+3]);
            }
        }
    }
}

extern "C" void kernel_launch(void* const* d_in, const int* in_sizes, int n_in,
                              void* d_out, int out_size, void* d_ws, size_t ws_size,
                              hipStream_t stream)
{
    const float* x       = (const float*)d_in[0];
    const float* w_spec1 = (const float*)d_in[1];
    const float* b_spec1 = (const float*)d_in[2];
    const float* w_spec2 = (const float*)d_in[3];
    const float* b_spec2 = (const float*)d_in[4];
    const float* g_bn1   = (const float*)d_in[5];
    const float* b_bn1   = (const float*)d_in[6];
    const float* g_bn2   = (const float*)d_in[7];
    const float* b_bn2   = (const float*)d_in[8];
    const float* w_sp1a  = (const float*)d_in[9];
    const float* g_bn3   = (const float*)d_in[10];
    const float* b_bn3   = (const float*)d_in[11];
    const float* w_sp1b  = (const float*)d_in[12];
    const float* b_sp1b  = (const float*)d_in[13];
    const float* g_bn4   = (const float*)d_in[14];
    const float* b_bn4   = (const float*)d_in[15];
    const float* w_sp2   = (const float*)d_in[16];
    const float* b_sp2   = (const float*)d_in[17];
    const float* g_bn5   = (const float*)d_in[18];
    const float* b_bn5   = (const float*)d_in[19];
    const float* Amat    = (const float*)d_in[20];
    const float* Bmat    = (const float*)d_in[21];
    const float* Cmat    = (const float*)d_in[22];
    const float* qkv_w   = (const float*)d_in[23];
    const float* qkv_b   = (const float*)d_in[24];
    const float* proj_w  = (const float*)d_in[25];
    const float* proj_b  = (const float*)d_in[26];
    const float* ff1_w   = (const float*)d_in[27];
    const float* ff1_b   = (const float*)d_in[28];
    const float* ff2_w   = (const float*)d_in[29];
    const float* ff2_b   = (const float*)d_in[30];
    const float* ln1_g   = (const float*)d_in[31];
    const float* ln1_b   = (const float*)d_in[32];
    const float* ln2_g   = (const float*)d_in[33];
    const float* ln2_b   = (const float*)d_in[34];

    float* ws  = (float*)d_ws;
    float* out = (float*)d_out;

    float* consts = ws + OFF_CONST;
    float* chnk   = ws + OFF_CHNK;
    float* seq    = ws + OFF_SEQ;
    float* stbuf  = ws + OFF_STB;
    float* hbuf   = ws + OFF_HBUF;

    k_setup<<<24, 256, 0, stream>>>(w_sp1a, b_spec1, g_bn1, b_bn1, g_bn3, b_bn3,
                                    w_spec2, b_spec2, g_bn2, b_bn2,
                                    w_sp2, b_sp2, g_bn5, b_bn5, w_spec1, consts);
    k_front<<<BBATCH*4 + BBATCH*4, 256, 0, stream>>>(x, consts,
        w_sp1b, b_sp1b, g_bn4, b_bn4, seq, chnk);
    k_ssm<<<BBATCH/4, 64, 0, stream>>>(seq, chnk, Amat, Bmat, stbuf);

    k_tfl<<<LSEQ*4, 256, 0, stream>>>(stbuf, Cmat, 1,
        qkv_w, qkv_b, proj_w, proj_b, ff1_w, ff1_b, ff2_w, ff2_b,
        ln1_g, ln1_b, ln2_g, ln2_b, hbuf, out, 0);
    k_tfl<<<LSEQ*4, 256, 0, stream>>>(hbuf, Cmat, 0,
        qkv_w + 768, qkv_b + 48, proj_w + 256, proj_b + 16,
        ff1_w + 1024, ff1_b + 64, ff2_w + 1024, ff2_b + 16,
        ln1_g + 16, ln1_b + 16, ln2_g + 16, ln2_b + 16, hbuf, out, 1);
}